// Round 2
// baseline (170.273 us; speedup 1.0000x reference)
//
#include <hip/hip_runtime.h>
#include <hip/hip_fp16.h>

#define N_NODES 100000
#define N_RELS  2000
#define D       128
#define DEG     16

// ws layout: [ relws: 2000*float2 (padded to 16384B) | feat16 | rel16 ]
#define RELWS_BYTES  16384
#define FEAT16_BYTES ((size_t)N_NODES * D * 2)   // 25,600,000
#define REL16_BYTES  ((size_t)N_RELS * D * 2)    // 512,000
#define WS_NEED      (RELWS_BYTES + FEAT16_BYTES + REL16_BYTES)

typedef unsigned int u32x4 __attribute__((ext_vector_type(4)));

static __device__ __forceinline__ __half2 bc_h2(unsigned int u) {
  return __builtin_bit_cast(__half2, u);
}
static __device__ __forceinline__ int bc_i(float f) {
  return __builtin_bit_cast(int, f);
}
static __device__ __forceinline__ float bc_f(int i) {
  return __builtin_bit_cast(float, i);
}

// Sum across each 16-lane row, result broadcast to all 16 lanes.
// Pure-DPP butterfly: xor1 (quad_perm [1,0,3,2]), xor2 (quad_perm [2,3,0,1]),
// then rotate-by-4 and rotate-by-8 within the 16-lane row. After the two
// quad_perm steps every quad holds its quad-sum in all 4 lanes; the two
// rotations then sum all 4 quads into every lane. No LDS pipe usage at all
// (the previous version's ds_swizzle was ~120cy of serial LDS latency per
// iteration and the source of SQ_LDS_BANK_CONFLICT).
static __device__ __forceinline__ float row16_sum_bcast(float v) {
  v += bc_f(__builtin_amdgcn_update_dpp(0, bc_i(v), 0x0B1, 0xF, 0xF, false)); // quad_perm [1,0,3,2] (xor1)
  v += bc_f(__builtin_amdgcn_update_dpp(0, bc_i(v), 0x04E, 0xF, 0xF, false)); // quad_perm [2,3,0,1] (xor2)
  v += bc_f(__builtin_amdgcn_update_dpp(0, bc_i(v), 0x124, 0xF, 0xF, false)); // row_ror:4
  v += bc_f(__builtin_amdgcn_update_dpp(0, bc_i(v), 0x128, 0xF, 0xF, false)); // row_ror:8
  return v;
}

// ---------- fused pre-pass: feature fp32->fp16 + per-relation precompute ----------
__global__ __launch_bounds__(256) void pre_kernel(
    const float* __restrict__ features,
    const float* __restrict__ rel_emb,
    const float* __restrict__ attn,
    float2* __restrict__ relws,
    unsigned int* __restrict__ rel16u,
    uint2* __restrict__ feat16v) {
  const int i = blockIdx.x * 256 + threadIdx.x;  // float4 index
  float4 v = ((const float4*)features)[i];
  uint2 o;
  o.x = __builtin_bit_cast(unsigned int, __builtin_amdgcn_cvt_pkrtz(v.x, v.y));
  o.y = __builtin_bit_cast(unsigned int, __builtin_amdgcn_cvt_pkrtz(v.z, v.w));
  feat16v[i] = o;

  if (blockIdx.x < N_RELS / 4) {
    const int wave = threadIdx.x >> 6;
    const int lane = threadIdx.x & 63;
    const int r = blockIdx.x * 4 + wave;
    float2 ev = *(const float2*)(rel_emb + (size_t)r * D + lane * 2);
    float2 av = *(const float2*)(attn + lane * 2);
    rel16u[r * 64 + lane] =
        __builtin_bit_cast(unsigned int, __builtin_amdgcn_cvt_pkrtz(ev.x, ev.y));
    float ss = ev.x * ev.x + ev.y * ev.y;
    float dt = ev.x * av.x + ev.y * av.y;
#pragma unroll
    for (int off = 32; off >= 1; off >>= 1) {
      ss += __shfl_xor(ss, off, 64);
      dt += __shfl_xor(dt, off, 64);
    }
    if (lane == 0) {
      float inv = rsqrtf(fmaxf(ss, 1e-12f));
      relws[r] = make_float2(inv, expf(dt));
    }
  }
}

// ---------- standalone rel precompute (fallback path only) ----------
__global__ __launch_bounds__(256) void rel_pre_kernel(
    const float* __restrict__ rel_emb,
    const float* __restrict__ attn,
    float2* __restrict__ relws,
    unsigned int* __restrict__ rel16u) {
  const int wave = threadIdx.x >> 6;
  const int lane = threadIdx.x & 63;
  const int r = blockIdx.x * 4 + wave;
  float2 ev = *(const float2*)(rel_emb + (size_t)r * D + lane * 2);
  float2 av = *(const float2*)(attn + lane * 2);
  rel16u[r * 64 + lane] =
      __builtin_bit_cast(unsigned int, __builtin_amdgcn_cvt_pkrtz(ev.x, ev.y));
  float ss = ev.x * ev.x + ev.y * ev.y;
  float dt = ev.x * av.x + ev.y * av.y;
#pragma unroll
  for (int off = 32; off >= 1; off >>= 1) {
    ss += __shfl_xor(ss, off, 64);
    dt += __shfl_xor(dt, off, 64);
  }
  if (lane == 0) {
    float inv = rsqrtf(fmaxf(ss, 1e-12f));
    relws[r] = make_float2(inv, expf(dt));
  }
}

// ---------- main kernel: enforced 8-deep gather pipeline ----------
// __launch_bounds__(256, 1): CRITICAL. With the default occupancy-greedy
// budget the backend capped the kernel at ~60 VGPRs and SPILLED the pipeline
// buffers to scratch (inserting vmcnt(0) after every load to feed the scratch
// store) — silently serializing all gathers. 8 pairs in flight needs 64 VGPRs
// for buffers alone; waves-per-EU=1 lifts the budget to 512 so the buffers
// stay resident. Expected ~140-170 VGPR -> 3 waves/SIMD, same as the measured
// stall-limited occupancy, so nothing is lost.

#define GAT_WAIT(n) asm volatile("s_waitcnt vmcnt(" #n ")")

#define GAT_ISSUE(slot, rx)                                                    \
  {                                                                            \
    const unsigned long long fo_ =                                             \
        (unsigned long long)(feat16 + (size_t)((rx) >> 11) * D + s * 8);       \
    const unsigned long long fe_ =                                             \
        (unsigned long long)(rel16 + (size_t)((rx) & 2047u) * D + s * 8);      \
    asm volatile("global_load_dwordx4 %0, %1, off"                             \
                 : "=v"(ofb[(slot)]) : "v"(fo_));                              \
    asm volatile("global_load_dwordx4 %0, %1, off"                             \
                 : "=v"(efb[(slot)]) : "v"(fe_));                              \
  }

#define GAT_ITER(i, vmw)                                                       \
  {                                                                            \
    GAT_WAIT(vmw);                                                             \
    __builtin_amdgcn_sched_barrier(0);                                         \
    const u32x4 of = ofb[(i) & 7];                                             \
    const u32x4 ef = efb[(i) & 7];                                             \
    const unsigned int ac = rc[(i)].y;                                         \
    if constexpr ((i) + 8 < DEG) GAT_ISSUE((i) & 7, rc[(i) + 8].x);            \
    const __half2 o0 = bc_h2(of.x), o1 = bc_h2(of.y), o2 = bc_h2(of.z),        \
                  o3 = bc_h2(of.w);                                            \
    const __half2 e0 = bc_h2(ef.x), e1 = bc_h2(ef.y), e2 = bc_h2(ef.z),        \
                  e3 = bc_h2(ef.w);                                            \
    __half2 pp = __hmul2(o0, e0);                                              \
    pp = __hfma2(o1, e1, pp);                                                  \
    pp = __hfma2(o2, e2, pp);                                                  \
    pp = __hfma2(o3, e3, pp);                                                  \
    const float pd = row16_sum_bcast(__low2float(pp) + __high2float(pp));      \
    const __half2 h = bc_h2(ac);                                               \
    const __half2 att2 = __half2half2(__low2half(h));                          \
    const __half2 c2 = __float2half2_rn(__high2float(h) * pd);                 \
    acc1[0] = __hfma2(att2, o0, acc1[0]);                                      \
    acc1[1] = __hfma2(att2, o1, acc1[1]);                                      \
    acc1[2] = __hfma2(att2, o2, acc1[2]);                                      \
    acc1[3] = __hfma2(att2, o3, acc1[3]);                                      \
    acc2[0] = __hfma2(c2, e0, acc2[0]);                                        \
    acc2[1] = __hfma2(c2, e1, acc2[1]);                                        \
    acc2[2] = __hfma2(c2, e2, acc2[2]);                                        \
    acc2[3] = __hfma2(c2, e3, acc2[3]);                                        \
  }

__global__ __launch_bounds__(256, 1) void gat16_kernel(
    const int* __restrict__ triples,
    const unsigned short* __restrict__ feat16,
    const unsigned short* __restrict__ rel16,
    const float2* __restrict__ relws,
    float* __restrict__ out) {
  __shared__ uint2 recs[256];  // one edge record per thread

  const int tid  = threadIdx.x;
  const int s    = tid & 15;
  const int g    = (tid >> 4) & 3;
  const int wave = tid >> 6;
  const int node = blockIdx.x * 16 + wave * 4 + g;

  // This lane's edge (node g, edge s): indices + (att, cf).
  const int* t = triples + (size_t)node * (DEG * 3);
  const int tr = t[3 * s + 1];
  const int to = t[3 * s + 2];
  const float2 ia = relws[tr];  // (inv_norm, att)
  const float att = ia.y;
  const float cf  = 2.f * att * ia.x;

  // den over the 16 edges of this node (once).
  float den = att;
  den += __shfl_xor(den, 1);
  den += __shfl_xor(den, 2);
  den += __shfl_xor(den, 4);
  den += __shfl_xor(den, 8);
  const float rden = 1.f / den;

  // Stage edge record: idx packed (to:17b | tr:11b), (att,cf) as half2.
  recs[tid] = make_uint2(
      (unsigned int)((to << 11) | tr),
      __builtin_bit_cast(unsigned int, __builtin_amdgcn_cvt_pkrtz(att, cf)));
  __syncthreads();

  const int rbase = tid & 0xF0;  // wave*64 + g*16: first record of my node

  // Preload all 16 edge records of my node into registers (broadcast reads).
  uint2 rc[16];
#pragma unroll
  for (int i = 0; i < 16; ++i) rc[i] = recs[rbase + i];

  // Prologue: issue 8 edge-pairs (16 loads). vmcnt already 0 after barrier;
  // the explicit wait pins the baseline for the counted waits below.
  u32x4 ofb[8], efb[8];
  GAT_WAIT(0);
#pragma unroll
  for (int i = 0; i < 8; ++i) GAT_ISSUE(i, rc[i].x);

  __half2 acc1[4], acc2[4];
#pragma unroll
  for (int j = 0; j < 4; ++j) {
    acc1[j] = __float2half2_rn(0.f);
    acc2[j] = __float2half2_rn(0.f);
  }

  // Steady state: wait pair i (vmcnt 14 = 7 pairs still in flight), consume,
  // refill slot. Drain 14->0 over the last iterations.
  GAT_ITER(0, 14)  GAT_ITER(1, 14)  GAT_ITER(2, 14)  GAT_ITER(3, 14)
  GAT_ITER(4, 14)  GAT_ITER(5, 14)  GAT_ITER(6, 14)  GAT_ITER(7, 14)
  GAT_ITER(8, 14)  GAT_ITER(9, 12)  GAT_ITER(10, 10) GAT_ITER(11, 8)
  GAT_ITER(12, 6)  GAT_ITER(13, 4)  GAT_ITER(14, 2)  GAT_ITER(15, 0)

  // out[d] = (acc1 - acc2) / den for this lane's 8 dims
  float* op = out + (size_t)node * D + s * 8;
  float4 r0, r1;
  {
    float2 a0 = __half22float2(acc1[0]), b0 = __half22float2(acc2[0]);
    float2 a1 = __half22float2(acc1[1]), b1 = __half22float2(acc2[1]);
    r0.x = (a0.x - b0.x) * rden; r0.y = (a0.y - b0.y) * rden;
    r0.z = (a1.x - b1.x) * rden; r0.w = (a1.y - b1.y) * rden;
    float2 a2 = __half22float2(acc1[2]), b2 = __half22float2(acc2[2]);
    float2 a3 = __half22float2(acc1[3]), b3 = __half22float2(acc2[3]);
    r1.x = (a2.x - b2.x) * rden; r1.y = (a2.y - b2.y) * rden;
    r1.z = (a3.x - b3.x) * rden; r1.w = (a3.y - b3.y) * rden;
  }
  *(float4*)op = r0;
  *(float4*)(op + 4) = r1;
}

// ---------- fallback (fp32 path) if ws is too small ----------
__global__ __launch_bounds__(256) void gat_kernel(
    const int* __restrict__ triples,
    const float* __restrict__ features,
    const float* __restrict__ rel_emb,
    const float2* __restrict__ relws,
    float* __restrict__ out) {
  const int wave = threadIdx.x >> 6;
  const int lane = threadIdx.x & 63;
  const int node = blockIdx.x * 4 + wave;
  const int* t = triples + (size_t)node * DEG * 3;
  int tv = (lane < DEG * 3) ? t[lane] : 0;
  float2 acc = make_float2(0.f, 0.f);
  float den = 0.f;
#pragma unroll
  for (int i = 0; i < DEG; ++i) {
    const int rel = __builtin_amdgcn_readfirstlane(__shfl(tv, 3 * i + 1, 64));
    const int obj = __builtin_amdgcn_readfirstlane(__shfl(tv, 3 * i + 2, 64));
    float2 ia = relws[rel];
    float2 ov = *(const float2*)(features + (size_t)obj * D + lane * 2);
    float2 ev = *(const float2*)(rel_emb + (size_t)rel * D + lane * 2);
    float pd = ov.x * ev.x + ov.y * ev.y;
#pragma unroll
    for (int off = 32; off >= 1; off >>= 1) pd += __shfl_xor(pd, off, 64);
    const float c = 2.f * pd * ia.x;
    const float att = ia.y;
    acc.x += att * (ov.x - c * ev.x);
    acc.y += att * (ov.y - c * ev.y);
    den += att;
  }
  const float r = 1.f / den;
  *(float2*)(out + (size_t)node * D + lane * 2) =
      make_float2(acc.x * r, acc.y * r);
}

extern "C" void kernel_launch(void* const* d_in, const int* in_sizes, int n_in,
                              void* d_out, int out_size, void* d_ws, size_t ws_size,
                              hipStream_t stream) {
  const int*   triples  = (const int*)d_in[0];
  const float* features = (const float*)d_in[1];
  const float* rel_emb  = (const float*)d_in[2];
  const float* attn     = (const float*)d_in[3];
  float*       out      = (float*)d_out;

  float2* relws = (float2*)d_ws;

  if (ws_size >= WS_NEED) {
    unsigned short* feat16 = (unsigned short*)((char*)d_ws + RELWS_BYTES);
    unsigned int*   rel16u = (unsigned int*)((char*)d_ws + RELWS_BYTES + FEAT16_BYTES);
    pre_kernel<<<(N_NODES * D / 4) / 256, 256, 0, stream>>>(
        features, rel_emb, attn, relws, rel16u, (uint2*)feat16);
    gat16_kernel<<<N_NODES / 16, 256, 0, stream>>>(
        triples, feat16, (const unsigned short*)rel16u, relws, out);
  } else {
    rel_pre_kernel<<<N_RELS / 4, 256, 0, stream>>>(rel_emb, attn, relws,
                                                   (unsigned int*)d_ws);
    gat_kernel<<<N_NODES / 4, 256, 0, stream>>>(
        triples, features, rel_emb, relws, out);
  }
}

// Round 3
// 169.519 us; speedup vs baseline: 1.0044x; 1.0044x over previous
//
#include <hip/hip_runtime.h>
#include <hip/hip_fp16.h>

#define N_NODES 100000
#define N_RELS  2000
#define D       128
#define DEG     16

// ws layout: [ relws: 2000*float2 (padded to 16384B) | feat16 | rel16 ]
#define RELWS_BYTES  16384
#define FEAT16_BYTES ((size_t)N_NODES * D * 2)   // 25,600,000
#define REL16_BYTES  ((size_t)N_RELS * D * 2)    // 512,000
#define WS_NEED      (RELWS_BYTES + FEAT16_BYTES + REL16_BYTES)

typedef unsigned int u32x4 __attribute__((ext_vector_type(4)));

static __device__ __forceinline__ __half2 bc_h2(unsigned int u) {
  return __builtin_bit_cast(__half2, u);
}
static __device__ __forceinline__ int bc_i(float f) {
  return __builtin_bit_cast(int, f);
}
static __device__ __forceinline__ float bc_f(int i) {
  return __builtin_bit_cast(float, i);
}

// Sum across each 16-lane row, result broadcast to all 16 lanes.
// Pure-DPP butterfly (VALU pipe only, no LDS).
static __device__ __forceinline__ float row16_sum_bcast(float v) {
  v += bc_f(__builtin_amdgcn_update_dpp(0, bc_i(v), 0x0B1, 0xF, 0xF, false)); // quad_perm [1,0,3,2] (xor1)
  v += bc_f(__builtin_amdgcn_update_dpp(0, bc_i(v), 0x04E, 0xF, 0xF, false)); // quad_perm [2,3,0,1] (xor2)
  v += bc_f(__builtin_amdgcn_update_dpp(0, bc_i(v), 0x124, 0xF, 0xF, false)); // row_ror:4
  v += bc_f(__builtin_amdgcn_update_dpp(0, bc_i(v), 0x128, 0xF, 0xF, false)); // row_ror:8
  return v;
}

// ---------- fused pre-pass: feature fp32->fp16 + per-relation precompute ----------
__global__ __launch_bounds__(256) void pre_kernel(
    const float* __restrict__ features,
    const float* __restrict__ rel_emb,
    const float* __restrict__ attn,
    float2* __restrict__ relws,
    unsigned int* __restrict__ rel16u,
    uint2* __restrict__ feat16v) {
  const int i = blockIdx.x * 256 + threadIdx.x;  // float4 index
  float4 v = ((const float4*)features)[i];
  uint2 o;
  o.x = __builtin_bit_cast(unsigned int, __builtin_amdgcn_cvt_pkrtz(v.x, v.y));
  o.y = __builtin_bit_cast(unsigned int, __builtin_amdgcn_cvt_pkrtz(v.z, v.w));
  feat16v[i] = o;

  if (blockIdx.x < N_RELS / 4) {
    const int wave = threadIdx.x >> 6;
    const int lane = threadIdx.x & 63;
    const int r = blockIdx.x * 4 + wave;
    float2 ev = *(const float2*)(rel_emb + (size_t)r * D + lane * 2);
    float2 av = *(const float2*)(attn + lane * 2);
    rel16u[r * 64 + lane] =
        __builtin_bit_cast(unsigned int, __builtin_amdgcn_cvt_pkrtz(ev.x, ev.y));
    float ss = ev.x * ev.x + ev.y * ev.y;
    float dt = ev.x * av.x + ev.y * av.y;
#pragma unroll
    for (int off = 32; off >= 1; off >>= 1) {
      ss += __shfl_xor(ss, off, 64);
      dt += __shfl_xor(dt, off, 64);
    }
    if (lane == 0) {
      float inv = rsqrtf(fmaxf(ss, 1e-12f));
      relws[r] = make_float2(inv, expf(dt));
    }
  }
}

// ---------- standalone rel precompute (fallback path only) ----------
__global__ __launch_bounds__(256) void rel_pre_kernel(
    const float* __restrict__ rel_emb,
    const float* __restrict__ attn,
    float2* __restrict__ relws,
    unsigned int* __restrict__ rel16u) {
  const int wave = threadIdx.x >> 6;
  const int lane = threadIdx.x & 63;
  const int r = blockIdx.x * 4 + wave;
  float2 ev = *(const float2*)(rel_emb + (size_t)r * D + lane * 2);
  float2 av = *(const float2*)(attn + lane * 2);
  rel16u[r * 64 + lane] =
      __builtin_bit_cast(unsigned int, __builtin_amdgcn_cvt_pkrtz(ev.x, ev.y));
  float ss = ev.x * ev.x + ev.y * ev.y;
  float dt = ev.x * av.x + ev.y * av.y;
#pragma unroll
  for (int off = 32; off >= 1; off >>= 1) {
    ss += __shfl_xor(ss, off, 64);
    dt += __shfl_xor(dt, off, 64);
  }
  if (lane == 0) {
    float inv = rsqrtf(fmaxf(ss, 1e-12f));
    relws[r] = make_float2(inv, expf(dt));
  }
}

// ---------- main kernel: enforced 8-deep gather pipeline, NAMED registers ----------
// Rounds 1-2 post-mortem: the pipeline buffers were C arrays (allocas); the
// asm "=v"(ofb[slot]) outputs were writes into a GEP, SROA never promoted
// them, so all 16 load destinations lived in SCRATCH. Each asm load was
// followed by a compiler scratch-store with a serializing s_waitcnt — the
// pipeline never existed (VGPR_Count stayed 60; impossible to hold 64 regs
// of buffers). Fix per rule #20: NAMED scalars for every pipeline value.
// __launch_bounds__(256,3): cap ~168 VGPR (need ~130), 3 waves/SIMD.

#define GAT_WAIT(n) asm volatile("s_waitcnt vmcnt(" #n ")")

#define GAT_STAGE(ofv, efv, rx)                                                \
  {                                                                            \
    const unsigned long long fo_ =                                             \
        (unsigned long long)(feat16 + (size_t)((rx) >> 11) * D + s * 8);       \
    const unsigned long long fe_ =                                             \
        (unsigned long long)(rel16 + (size_t)((rx) & 2047u) * D + s * 8);      \
    asm volatile("global_load_dwordx4 %0, %1, off" : "=v"(ofv) : "v"(fo_));    \
    asm volatile("global_load_dwordx4 %0, %1, off" : "=v"(efv) : "v"(fe_));    \
  }

#define GAT_BODY(of, ef, ac)                                                   \
  {                                                                            \
    const __half2 o0 = bc_h2((of).x), o1 = bc_h2((of).y),                      \
                  o2 = bc_h2((of).z), o3 = bc_h2((of).w);                      \
    const __half2 e0 = bc_h2((ef).x), e1 = bc_h2((ef).y),                      \
                  e2 = bc_h2((ef).z), e3 = bc_h2((ef).w);                      \
    __half2 pp = __hmul2(o0, e0);                                              \
    pp = __hfma2(o1, e1, pp);                                                  \
    pp = __hfma2(o2, e2, pp);                                                  \
    pp = __hfma2(o3, e3, pp);                                                  \
    const float pd = row16_sum_bcast(__low2float(pp) + __high2float(pp));      \
    const __half2 h = bc_h2(ac);                                               \
    const __half2 att2 = __half2half2(__low2half(h));                          \
    const __half2 c2 = __float2half2_rn(__high2float(h) * pd);                 \
    acc1_0 = __hfma2(att2, o0, acc1_0);                                        \
    acc1_1 = __hfma2(att2, o1, acc1_1);                                        \
    acc1_2 = __hfma2(att2, o2, acc1_2);                                        \
    acc1_3 = __hfma2(att2, o3, acc1_3);                                        \
    acc2_0 = __hfma2(c2, e0, acc2_0);                                          \
    acc2_1 = __hfma2(c2, e1, acc2_1);                                          \
    acc2_2 = __hfma2(c2, e2, acc2_2);                                          \
    acc2_3 = __hfma2(c2, e3, acc2_3);                                          \
  }

// iter with refill: wait, fence, issue next pair (ASAP), then compute this pair
#define GAT_FULL(i, j, vmw)                                                    \
  GAT_WAIT(vmw);                                                               \
  __builtin_amdgcn_sched_barrier(0);                                           \
  GAT_STAGE(of##j, ef##j, rc##j.x);                                            \
  GAT_BODY(of##i, ef##i, rc##i.y)

// drain iter: no refill
#define GAT_LAST(i, vmw)                                                       \
  GAT_WAIT(vmw);                                                               \
  __builtin_amdgcn_sched_barrier(0);                                           \
  GAT_BODY(of##i, ef##i, rc##i.y)

__global__ __launch_bounds__(256, 3) void gat16_kernel(
    const int* __restrict__ triples,
    const unsigned short* __restrict__ feat16,
    const unsigned short* __restrict__ rel16,
    const float2* __restrict__ relws,
    float* __restrict__ out) {
  __shared__ uint2 recs[256];  // one edge record per thread

  const int tid  = threadIdx.x;
  const int s    = tid & 15;
  const int g    = (tid >> 4) & 3;
  const int wave = tid >> 6;
  const int node = blockIdx.x * 16 + wave * 4 + g;

  // This lane's edge (node g, edge s): indices + (att, cf).
  const int* t = triples + (size_t)node * (DEG * 3);
  const int tr = t[3 * s + 1];
  const int to = t[3 * s + 2];
  const float2 ia = relws[tr];  // (inv_norm, att)
  const float att = ia.y;
  const float cf  = 2.f * att * ia.x;

  // den over the 16 edges of this node (once).
  float den = att;
  den += __shfl_xor(den, 1);
  den += __shfl_xor(den, 2);
  den += __shfl_xor(den, 4);
  den += __shfl_xor(den, 8);
  const float rden = 1.f / den;

  // Stage edge record: idx packed (to:17b | tr:11b), (att,cf) as half2.
  recs[tid] = make_uint2(
      (unsigned int)((to << 11) | tr),
      __builtin_bit_cast(unsigned int, __builtin_amdgcn_cvt_pkrtz(att, cf)));
  __syncthreads();

  const int rbase = tid & 0xF0;  // wave*64 + g*16: first record of my node

  // Preload all 16 edge records into NAMED registers (broadcast LDS reads).
  const uint2 rc0  = recs[rbase + 0],  rc1  = recs[rbase + 1];
  const uint2 rc2  = recs[rbase + 2],  rc3  = recs[rbase + 3];
  const uint2 rc4  = recs[rbase + 4],  rc5  = recs[rbase + 5];
  const uint2 rc6  = recs[rbase + 6],  rc7  = recs[rbase + 7];
  const uint2 rc8  = recs[rbase + 8],  rc9  = recs[rbase + 9];
  const uint2 rc10 = recs[rbase + 10], rc11 = recs[rbase + 11];
  const uint2 rc12 = recs[rbase + 12], rc13 = recs[rbase + 13];
  const uint2 rc14 = recs[rbase + 14], rc15 = recs[rbase + 15];

  // Pipeline registers — all NAMED (SSA values, never memory).
  u32x4 of0, of1, of2, of3, of4, of5, of6, of7;
  u32x4 of8, of9, of10, of11, of12, of13, of14, of15;
  u32x4 ef0, ef1, ef2, ef3, ef4, ef5, ef6, ef7;
  u32x4 ef8, ef9, ef10, ef11, ef12, ef13, ef14, ef15;

  // Prologue: pin vmcnt baseline, then issue 8 edge-pairs (16 loads).
  GAT_WAIT(0);
  GAT_STAGE(of0, ef0, rc0.x);
  GAT_STAGE(of1, ef1, rc1.x);
  GAT_STAGE(of2, ef2, rc2.x);
  GAT_STAGE(of3, ef3, rc3.x);
  GAT_STAGE(of4, ef4, rc4.x);
  GAT_STAGE(of5, ef5, rc5.x);
  GAT_STAGE(of6, ef6, rc6.x);
  GAT_STAGE(of7, ef7, rc7.x);

  __half2 acc1_0 = __float2half2_rn(0.f), acc1_1 = __float2half2_rn(0.f);
  __half2 acc1_2 = __float2half2_rn(0.f), acc1_3 = __float2half2_rn(0.f);
  __half2 acc2_0 = __float2half2_rn(0.f), acc2_1 = __float2half2_rn(0.f);
  __half2 acc2_2 = __float2half2_rn(0.f), acc2_3 = __float2half2_rn(0.f);

  // Steady state: 8 pairs (16 loads) in flight; wait vmcnt(14) retires the
  // oldest pair; refill keeps depth. Drain 14->0 over the last 8 iterations.
  GAT_FULL(0, 8, 14);
  GAT_FULL(1, 9, 14);
  GAT_FULL(2, 10, 14);
  GAT_FULL(3, 11, 14);
  GAT_FULL(4, 12, 14);
  GAT_FULL(5, 13, 14);
  GAT_FULL(6, 14, 14);
  GAT_FULL(7, 15, 14);
  GAT_LAST(8, 14);
  GAT_LAST(9, 12);
  GAT_LAST(10, 10);
  GAT_LAST(11, 8);
  GAT_LAST(12, 6);
  GAT_LAST(13, 4);
  GAT_LAST(14, 2);
  GAT_LAST(15, 0);

  // out[d] = (acc1 - acc2) / den for this lane's 8 dims
  float* op = out + (size_t)node * D + s * 8;
  float4 r0, r1;
  {
    float2 a0 = __half22float2(acc1_0), b0 = __half22float2(acc2_0);
    float2 a1 = __half22float2(acc1_1), b1 = __half22float2(acc2_1);
    r0.x = (a0.x - b0.x) * rden; r0.y = (a0.y - b0.y) * rden;
    r0.z = (a1.x - b1.x) * rden; r0.w = (a1.y - b1.y) * rden;
    float2 a2 = __half22float2(acc1_2), b2 = __half22float2(acc2_2);
    float2 a3 = __half22float2(acc1_3), b3 = __half22float2(acc2_3);
    r1.x = (a2.x - b2.x) * rden; r1.y = (a2.y - b2.y) * rden;
    r1.z = (a3.x - b3.x) * rden; r1.w = (a3.y - b3.y) * rden;
  }
  *(float4*)op = r0;
  *(float4*)(op + 4) = r1;
}

// ---------- fallback (fp32 path) if ws is too small ----------
__global__ __launch_bounds__(256) void gat_kernel(
    const int* __restrict__ triples,
    const float* __restrict__ features,
    const float* __restrict__ rel_emb,
    const float2* __restrict__ relws,
    float* __restrict__ out) {
  const int wave = threadIdx.x >> 6;
  const int lane = threadIdx.x & 63;
  const int node = blockIdx.x * 4 + wave;
  const int* t = triples + (size_t)node * DEG * 3;
  int tv = (lane < DEG * 3) ? t[lane] : 0;
  float2 acc = make_float2(0.f, 0.f);
  float den = 0.f;
#pragma unroll
  for (int i = 0; i < DEG; ++i) {
    const int rel = __builtin_amdgcn_readfirstlane(__shfl(tv, 3 * i + 1, 64));
    const int obj = __builtin_amdgcn_readfirstlane(__shfl(tv, 3 * i + 2, 64));
    float2 ia = relws[rel];
    float2 ov = *(const float2*)(features + (size_t)obj * D + lane * 2);
    float2 ev = *(const float2*)(rel_emb + (size_t)rel * D + lane * 2);
    float pd = ov.x * ev.x + ov.y * ev.y;
#pragma unroll
    for (int off = 32; off >= 1; off >>= 1) pd += __shfl_xor(pd, off, 64);
    const float c = 2.f * pd * ia.x;
    const float att = ia.y;
    acc.x += att * (ov.x - c * ev.x);
    acc.y += att * (ov.y - c * ev.y);
    den += att;
  }
  const float r = 1.f / den;
  *(float2*)(out + (size_t)node * D + lane * 2) =
      make_float2(acc.x * r, acc.y * r);
}

extern "C" void kernel_launch(void* const* d_in, const int* in_sizes, int n_in,
                              void* d_out, int out_size, void* d_ws, size_t ws_size,
                              hipStream_t stream) {
  const int*   triples  = (const int*)d_in[0];
  const float* features = (const float*)d_in[1];
  const float* rel_emb  = (const float*)d_in[2];
  const float* attn     = (const float*)d_in[3];
  float*       out      = (float*)d_out;

  float2* relws = (float2*)d_ws;

  if (ws_size >= WS_NEED) {
    unsigned short* feat16 = (unsigned short*)((char*)d_ws + RELWS_BYTES);
    unsigned int*   rel16u = (unsigned int*)((char*)d_ws + RELWS_BYTES + FEAT16_BYTES);
    pre_kernel<<<(N_NODES * D / 4) / 256, 256, 0, stream>>>(
        features, rel_emb, attn, relws, rel16u, (uint2*)feat16);
    gat16_kernel<<<N_NODES / 16, 256, 0, stream>>>(
        triples, feat16, (const unsigned short*)rel16u, relws, out);
  } else {
    rel_pre_kernel<<<N_RELS / 4, 256, 0, stream>>>(rel_emb, attn, relws,
                                                   (unsigned int*)d_ws);
    gat_kernel<<<N_NODES / 4, 256, 0, stream>>>(
        triples, features, rel_emb, relws, out);
  }
}

// Round 5
// 168.097 us; speedup vs baseline: 1.0129x; 1.0085x over previous
//
#include <hip/hip_runtime.h>
#include <hip/hip_fp16.h>

#define N_NODES 100000
#define N_RELS  2000
#define D       128
#define DEG     16
#define PIPE    6   // ring slots per wave (2KB each)

// ws layout: [ relws: 2000*float2 (padded to 16384B) | feat16 | rel16 ]
#define RELWS_BYTES  16384
#define FEAT16_BYTES ((size_t)N_NODES * D * 2)   // 25,600,000
#define REL16_BYTES  ((size_t)N_RELS * D * 2)    // 512,000
#define WS_NEED      (RELWS_BYTES + FEAT16_BYTES + REL16_BYTES)

typedef unsigned int u32x4 __attribute__((ext_vector_type(4)));

static __device__ __forceinline__ __half2 bc_h2(unsigned int u) {
  return __builtin_bit_cast(__half2, u);
}
static __device__ __forceinline__ int bc_i(float f) {
  return __builtin_bit_cast(int, f);
}
static __device__ __forceinline__ float bc_f(int i) {
  return __builtin_bit_cast(float, i);
}

// global -> LDS direct DMA, 16B per lane. LDS dest is wave-uniform base;
// hardware adds lane*16. No register destination => nothing to spill:
// this is why the pipeline survives the compiler where rounds 1-3 didn't.
static __device__ __forceinline__ void ldsdma16(const void* g, void* l) {
  __builtin_amdgcn_global_load_lds(
      (const __attribute__((address_space(1))) unsigned int*)g,
      (__attribute__((address_space(3))) unsigned int*)l, 16, 0, 0);
}

// Sum across each 16-lane row, result broadcast to all 16 lanes.
// Pure-DPP butterfly (VALU pipe only, no LDS).
static __device__ __forceinline__ float row16_sum_bcast(float v) {
  v += bc_f(__builtin_amdgcn_update_dpp(0, bc_i(v), 0x0B1, 0xF, 0xF, false)); // quad_perm [1,0,3,2] (xor1)
  v += bc_f(__builtin_amdgcn_update_dpp(0, bc_i(v), 0x04E, 0xF, 0xF, false)); // quad_perm [2,3,0,1] (xor2)
  v += bc_f(__builtin_amdgcn_update_dpp(0, bc_i(v), 0x124, 0xF, 0xF, false)); // row_ror:4
  v += bc_f(__builtin_amdgcn_update_dpp(0, bc_i(v), 0x128, 0xF, 0xF, false)); // row_ror:8
  return v;
}

// ---------- fused pre-pass: feature fp32->fp16 + per-relation precompute ----------
__global__ __launch_bounds__(256) void pre_kernel(
    const float* __restrict__ features,
    const float* __restrict__ rel_emb,
    const float* __restrict__ attn,
    float2* __restrict__ relws,
    unsigned int* __restrict__ rel16u,
    uint2* __restrict__ feat16v) {
  const int i = blockIdx.x * 256 + threadIdx.x;  // float4 index
  float4 v = ((const float4*)features)[i];
  uint2 o;
  o.x = __builtin_bit_cast(unsigned int, __builtin_amdgcn_cvt_pkrtz(v.x, v.y));
  o.y = __builtin_bit_cast(unsigned int, __builtin_amdgcn_cvt_pkrtz(v.z, v.w));
  feat16v[i] = o;

  if (blockIdx.x < N_RELS / 4) {
    const int wave = threadIdx.x >> 6;
    const int lane = threadIdx.x & 63;
    const int r = blockIdx.x * 4 + wave;
    float2 ev = *(const float2*)(rel_emb + (size_t)r * D + lane * 2);
    float2 av = *(const float2*)(attn + lane * 2);
    rel16u[r * 64 + lane] =
        __builtin_bit_cast(unsigned int, __builtin_amdgcn_cvt_pkrtz(ev.x, ev.y));
    float ss = ev.x * ev.x + ev.y * ev.y;
    float dt = ev.x * av.x + ev.y * av.y;
#pragma unroll
    for (int off = 32; off >= 1; off >>= 1) {
      ss += __shfl_xor(ss, off, 64);
      dt += __shfl_xor(dt, off, 64);
    }
    if (lane == 0) {
      float inv = rsqrtf(fmaxf(ss, 1e-12f));
      relws[r] = make_float2(inv, expf(dt));
    }
  }
}

// ---------- standalone rel precompute (fallback path only) ----------
__global__ __launch_bounds__(256) void rel_pre_kernel(
    const float* __restrict__ rel_emb,
    const float* __restrict__ attn,
    float2* __restrict__ relws,
    unsigned int* __restrict__ rel16u) {
  const int wave = threadIdx.x >> 6;
  const int lane = threadIdx.x & 63;
  const int r = blockIdx.x * 4 + wave;
  float2 ev = *(const float2*)(rel_emb + (size_t)r * D + lane * 2);
  float2 av = *(const float2*)(attn + lane * 2);
  rel16u[r * 64 + lane] =
      __builtin_bit_cast(unsigned int, __builtin_amdgcn_cvt_pkrtz(ev.x, ev.y));
  float ss = ev.x * ev.x + ev.y * ev.y;
  float dt = ev.x * av.x + ev.y * av.y;
#pragma unroll
  for (int off = 32; off >= 1; off >>= 1) {
    ss += __shfl_xor(ss, off, 64);
    dt += __shfl_xor(dt, off, 64);
  }
  if (lane == 0) {
    float inv = rsqrtf(fmaxf(ss, 1e-12f));
    relws[r] = make_float2(inv, expf(dt));
  }
}

// ---------- main kernel: LDS-ring gather pipeline (depth 6, counted vmcnt) ----------
// Rounds 1-3 post-mortem: any register-destination pipeline gets demoted to
// scratch by the allocator (VGPR_Count stuck at 56-64 across 3 structurally
// different attempts). global_load_lds has NO register destination: in-flight
// data lives in the vmcnt queue + LDS. Wave-private 6-slot ring, 2KB/slot
// (1KB feat quad-row + 1KB rel quad-row); lane reads back its own 16B chunk
// via asm ds_read_b128 (asm so the compiler cannot see the DMA dependency and
// insert a draining vmcnt(0)). Steady-state wait: vmcnt(10) = 5 pairs still
// in flight. No s_barrier in the loop (ring is wave-private).

#define GAT_WAITV(n) asm volatile("s_waitcnt vmcnt(" #n ")" ::: "memory")
#define GAT_WAITL()  asm volatile("s_waitcnt lgkmcnt(0)" ::: "memory")
#define GAT_SB()     __builtin_amdgcn_sched_barrier(0)

#define GAT_STAGE(slot, rx)                                                    \
  {                                                                            \
    ldsdma16(feat16 + (size_t)((rx) >> 11) * D + s * 8,                        \
             (void*)&ring[wave][(slot)][0]);                                   \
    ldsdma16(rel16 + (size_t)((rx) & 2047u) * D + s * 8,                       \
             (void*)&ring[wave][(slot)][64]);                                  \
  }

#define GAT_BODY(of, ef, ac)                                                   \
  {                                                                            \
    const __half2 o0 = bc_h2((of).x), o1 = bc_h2((of).y),                      \
                  o2 = bc_h2((of).z), o3 = bc_h2((of).w);                      \
    const __half2 e0 = bc_h2((ef).x), e1 = bc_h2((ef).y),                      \
                  e2 = bc_h2((ef).z), e3 = bc_h2((ef).w);                      \
    __half2 pp = __hmul2(o0, e0);                                              \
    pp = __hfma2(o1, e1, pp);                                                  \
    pp = __hfma2(o2, e2, pp);                                                  \
    pp = __hfma2(o3, e3, pp);                                                  \
    const float pd = row16_sum_bcast(__low2float(pp) + __high2float(pp));      \
    const __half2 h = bc_h2(ac);                                               \
    const __half2 att2 = __half2half2(__low2half(h));                          \
    const __half2 c2 = __float2half2_rn(__high2float(h) * pd);                 \
    acc1_0 = __hfma2(att2, o0, acc1_0);                                        \
    acc1_1 = __hfma2(att2, o1, acc1_1);                                        \
    acc1_2 = __hfma2(att2, o2, acc1_2);                                        \
    acc1_3 = __hfma2(att2, o3, acc1_3);                                        \
    acc2_0 = __hfma2(c2, e0, acc2_0);                                          \
    acc2_1 = __hfma2(c2, e1, acc2_1);                                          \
    acc2_2 = __hfma2(c2, e2, acc2_2);                                          \
    acc2_3 = __hfma2(c2, e3, acc2_3);                                          \
  }

// consume slot + re-stage it for pair (i+PIPE)
#define GAT_CONS_S(slot, vmw, rcur, rnext)                                     \
  {                                                                            \
    GAT_WAITV(vmw);                                                            \
    GAT_SB();                                                                  \
    u32x4 of_, ef_;                                                            \
    const unsigned fa_ = rb + (slot) * 2048;                                   \
    asm volatile("ds_read_b128 %0, %1" : "=v"(of_) : "v"(fa_));                \
    asm volatile("ds_read_b128 %0, %1 offset:1024" : "=v"(ef_) : "v"(fa_));    \
    GAT_WAITL();                                                               \
    GAT_SB();                                                                  \
    GAT_STAGE((slot), rnext.x);                                                \
    GAT_SB();                                                                  \
    GAT_BODY(of_, ef_, rcur.y);                                                \
  }

// consume only (drain tail)
#define GAT_CONS_D(slot, vmw, rcur)                                            \
  {                                                                            \
    GAT_WAITV(vmw);                                                            \
    GAT_SB();                                                                  \
    u32x4 of_, ef_;                                                            \
    const unsigned fa_ = rb + (slot) * 2048;                                   \
    asm volatile("ds_read_b128 %0, %1" : "=v"(of_) : "v"(fa_));                \
    asm volatile("ds_read_b128 %0, %1 offset:1024" : "=v"(ef_) : "v"(fa_));    \
    GAT_WAITL();                                                               \
    GAT_SB();                                                                  \
    GAT_BODY(of_, ef_, rcur.y);                                                \
  }

__global__ __launch_bounds__(256) void gat16_kernel(
    const int* __restrict__ triples,
    const unsigned short* __restrict__ feat16,
    const unsigned short* __restrict__ rel16,
    const float2* __restrict__ relws,
    float* __restrict__ out) {
  __shared__ uint2 recs[256];              // one edge record per thread
  __shared__ uint4 ring[4][PIPE][128];     // per-wave 6-slot ring, 2KB/slot

  const int tid  = threadIdx.x;
  const int s    = tid & 15;
  const int g    = (tid >> 4) & 3;
  const int wave = tid >> 6;
  const int node = blockIdx.x * 16 + wave * 4 + g;

  // This lane's edge (node g, edge s): indices + (att, cf).
  const int* t = triples + (size_t)node * (DEG * 3);
  const int tr = t[3 * s + 1];
  const int to = t[3 * s + 2];
  const float2 ia = relws[tr];  // (inv_norm, att)
  const float att = ia.y;
  const float cf  = 2.f * att * ia.x;

  // den over the 16 edges of this node (once).
  float den = att;
  den += __shfl_xor(den, 1);
  den += __shfl_xor(den, 2);
  den += __shfl_xor(den, 4);
  den += __shfl_xor(den, 8);
  const float rden = 1.f / den;

  // Stage edge record: idx packed (to:17b | tr:11b), (att,cf) as half2.
  recs[tid] = make_uint2(
      (unsigned int)((to << 11) | tr),
      __builtin_bit_cast(unsigned int, __builtin_amdgcn_cvt_pkrtz(att, cf)));
  __syncthreads();

  const int rbase = tid & 0xF0;  // wave*64 + g*16: first record of my node

  // Preload all 16 edge records into named registers (broadcast LDS reads).
  const uint2 rc0  = recs[rbase + 0],  rc1  = recs[rbase + 1];
  const uint2 rc2  = recs[rbase + 2],  rc3  = recs[rbase + 3];
  const uint2 rc4  = recs[rbase + 4],  rc5  = recs[rbase + 5];
  const uint2 rc6  = recs[rbase + 6],  rc7  = recs[rbase + 7];
  const uint2 rc8  = recs[rbase + 8],  rc9  = recs[rbase + 9];
  const uint2 rc10 = recs[rbase + 10], rc11 = recs[rbase + 11];
  const uint2 rc12 = recs[rbase + 12], rc13 = recs[rbase + 13];
  const uint2 rc14 = recs[rbase + 14], rc15 = recs[rbase + 15];

  // 32-bit LDS byte offset of this lane's 16B chunk in slot 0 of my ring.
  // (low 32 bits of a generic shared pointer == LDS offset; apertures are
  // 4GB-aligned)
  const unsigned rb =
      (unsigned)(unsigned long long)&ring[wave][0][0] + (tid & 63) * 16;

  __half2 acc1_0 = __float2half2_rn(0.f), acc1_1 = __float2half2_rn(0.f);
  __half2 acc1_2 = __float2half2_rn(0.f), acc1_3 = __float2half2_rn(0.f);
  __half2 acc2_0 = __float2half2_rn(0.f), acc2_1 = __float2half2_rn(0.f);
  __half2 acc2_2 = __float2half2_rn(0.f), acc2_3 = __float2half2_rn(0.f);

  // Prologue: pin vmcnt baseline, fill the ring (6 pairs = 12 DMAs).
  GAT_WAITV(0);
  GAT_STAGE(0, rc0.x);
  GAT_STAGE(1, rc1.x);
  GAT_STAGE(2, rc2.x);
  GAT_STAGE(3, rc3.x);
  GAT_STAGE(4, rc4.x);
  GAT_STAGE(5, rc5.x);

  // Steady state: wait vmcnt(10) retires the oldest pair; re-stage keeps
  // depth 6. Drain 10->0 over the last 6 iterations.
  GAT_CONS_S(0, 10, rc0, rc6);
  GAT_CONS_S(1, 10, rc1, rc7);
  GAT_CONS_S(2, 10, rc2, rc8);
  GAT_CONS_S(3, 10, rc3, rc9);
  GAT_CONS_S(4, 10, rc4, rc10);
  GAT_CONS_S(5, 10, rc5, rc11);
  GAT_CONS_S(0, 10, rc6, rc12);
  GAT_CONS_S(1, 10, rc7, rc13);
  GAT_CONS_S(2, 10, rc8, rc14);
  GAT_CONS_S(3, 10, rc9, rc15);
  GAT_CONS_D(4, 10, rc10);
  GAT_CONS_D(5, 8,  rc11);
  GAT_CONS_D(0, 6,  rc12);
  GAT_CONS_D(1, 4,  rc13);
  GAT_CONS_D(2, 2,  rc14);
  GAT_CONS_D(3, 0,  rc15);

  // out[d] = (acc1 - acc2) / den for this lane's 8 dims
  float* op = out + (size_t)node * D + s * 8;
  float4 r0, r1;
  {
    float2 a0 = __half22float2(acc1_0), b0 = __half22float2(acc2_0);
    float2 a1 = __half22float2(acc1_1), b1 = __half22float2(acc2_1);
    r0.x = (a0.x - b0.x) * rden; r0.y = (a0.y - b0.y) * rden;
    r0.z = (a1.x - b1.x) * rden; r0.w = (a1.y - b1.y) * rden;
    float2 a2 = __half22float2(acc1_2), b2 = __half22float2(acc2_2);
    float2 a3 = __half22float2(acc1_3), b3 = __half22float2(acc2_3);
    r1.x = (a2.x - b2.x) * rden; r1.y = (a2.y - b2.y) * rden;
    r1.z = (a3.x - b3.x) * rden; r1.w = (a3.y - b3.y) * rden;
  }
  *(float4*)op = r0;
  *(float4*)(op + 4) = r1;
}

// ---------- fallback (fp32 path) if ws is too small ----------
__global__ __launch_bounds__(256) void gat_kernel(
    const int* __restrict__ triples,
    const float* __restrict__ features,
    const float* __restrict__ rel_emb,
    const float2* __restrict__ relws,
    float* __restrict__ out) {
  const int wave = threadIdx.x >> 6;
  const int lane = threadIdx.x & 63;
  const int node = blockIdx.x * 4 + wave;
  const int* t = triples + (size_t)node * DEG * 3;
  int tv = (lane < DEG * 3) ? t[lane] : 0;
  float2 acc = make_float2(0.f, 0.f);
  float den = 0.f;
#pragma unroll
  for (int i = 0; i < DEG; ++i) {
    const int rel = __builtin_amdgcn_readfirstlane(__shfl(tv, 3 * i + 1, 64));
    const int obj = __builtin_amdgcn_readfirstlane(__shfl(tv, 3 * i + 2, 64));
    float2 ia = relws[rel];
    float2 ov = *(const float2*)(features + (size_t)obj * D + lane * 2);
    float2 ev = *(const float2*)(rel_emb + (size_t)rel * D + lane * 2);
    float pd = ov.x * ev.x + ov.y * ev.y;
#pragma unroll
    for (int off = 32; off >= 1; off >>= 1) pd += __shfl_xor(pd, off, 64);
    const float c = 2.f * pd * ia.x;
    const float att = ia.y;
    acc.x += att * (ov.x - c * ev.x);
    acc.y += att * (ov.y - c * ev.y);
    den += att;
  }
  const float r = 1.f / den;
  *(float2*)(out + (size_t)node * D + lane * 2) =
      make_float2(acc.x * r, acc.y * r);
}

extern "C" void kernel_launch(void* const* d_in, const int* in_sizes, int n_in,
                              void* d_out, int out_size, void* d_ws, size_t ws_size,
                              hipStream_t stream) {
  const int*   triples  = (const int*)d_in[0];
  const float* features = (const float*)d_in[1];
  const float* rel_emb  = (const float*)d_in[2];
  const float* attn     = (const float*)d_in[3];
  float*       out      = (float*)d_out;

  float2* relws = (float2*)d_ws;

  if (ws_size >= WS_NEED) {
    unsigned short* feat16 = (unsigned short*)((char*)d_ws + RELWS_BYTES);
    unsigned int*   rel16u = (unsigned int*)((char*)d_ws + RELWS_BYTES + FEAT16_BYTES);
    pre_kernel<<<(N_NODES * D / 4) / 256, 256, 0, stream>>>(
        features, rel_emb, attn, relws, rel16u, (uint2*)feat16);
    gat16_kernel<<<N_NODES / 16, 256, 0, stream>>>(
        triples, feat16, (const unsigned short*)rel16u, relws, out);
  } else {
    rel_pre_kernel<<<N_RELS / 4, 256, 0, stream>>>(rel_emb, attn, relws,
                                                   (unsigned int*)d_ws);
    gat_kernel<<<N_NODES / 4, 256, 0, stream>>>(
        triples, features, rel_emb, relws, out);
  }
}